// Round 1
// baseline (182.335 us; speedup 1.0000x reference)
//
#include <hip/hip_runtime.h>
#include <math.h>

#define THREADS 256
#define BPB 8  // bins per block in the term1 (per-bin min over pixels) path

__device__ __forceinline__ float wredMax(float v) {
  #pragma unroll
  for (int o = 32; o > 0; o >>= 1) v = fmaxf(v, __shfl_down(v, o, 64));
  return v;
}
__device__ __forceinline__ float wredMin(float v) {
  #pragma unroll
  for (int o = 32; o > 0; o >>= 1) v = fminf(v, __shfl_down(v, o, 64));
  return v;
}
__device__ __forceinline__ float wredSum(float v) {
  #pragma unroll
  for (int o = 32; o > 0; o >>= 1) v += __shfl_down(v, o, 64);
  return v;
}

// ws layout: [0] uint tmax_bits, [1] float bmax, bytes 8..15: double sum
__global__ __launch_bounds__(THREADS) void k_init(const float* __restrict__ bins, int nb,
                                                  unsigned int* wsu, float* wsf,
                                                  double* wsum) {
  __shared__ float sm[4];
  float v = -1e30f;
  for (int i = threadIdx.x; i < nb; i += THREADS) v = fmaxf(v, bins[i]);
  v = wredMax(v);
  int lane = threadIdx.x & 63, wid = threadIdx.x >> 6;
  if (lane == 0) sm[wid] = v;
  __syncthreads();
  if (threadIdx.x == 0) {
    wsf[1] = fmaxf(fmaxf(sm[0], sm[1]), fmaxf(sm[2], sm[3]));
    wsu[0] = 0u;       // tmax accumulator (positive floats: uint order == float order)
    wsum[0] = 0.0;     // chamfer sum accumulator
  }
}

__global__ __launch_bounds__(THREADS) void k_tmax(const float4* __restrict__ t4, int n4,
                                                  const float* __restrict__ t, int n,
                                                  unsigned int* wsu) {
  __shared__ float sm[4];
  float v = 0.0f;  // target values are > 0
  int idx = blockIdx.x * THREADS + threadIdx.x;
  int stride = gridDim.x * THREADS;
  for (int i = idx; i < n4; i += stride) {
    float4 a = t4[i];
    v = fmaxf(v, fmaxf(fmaxf(a.x, a.y), fmaxf(a.z, a.w)));
  }
  for (int i = n4 * 4 + idx; i < n; i += stride) v = fmaxf(v, t[i]);
  v = wredMax(v);
  int lane = threadIdx.x & 63, wid = threadIdx.x >> 6;
  if (lane == 0) sm[wid] = v;
  __syncthreads();
  if (threadIdx.x == 0) {
    float m = fmaxf(fmaxf(sm[0], sm[1]), fmaxf(sm[2], sm[3]));
    atomicMax(wsu, __float_as_uint(m));
  }
}

// blocks [0, t1b): term1 — each block owns BPB bins, scans all pixels, min per bin
// blocks [t1b, gridDim): term2 — per-pixel min over all bins (bins staged in LDS)
__global__ __launch_bounds__(THREADS) void k_main(const float4* __restrict__ t4, int n4,
                                                  const float* __restrict__ t, int n,
                                                  const float* __restrict__ bins, int nb,
                                                  const unsigned int* __restrict__ wsu,
                                                  const float* __restrict__ wsf,
                                                  double* wsum, int t1b) {
  const float it = 1.0f / __uint_as_float(wsu[0]);
  const float ib = 1.0f / wsf[1];
  const int lane = threadIdx.x & 63, wid = threadIdx.x >> 6;

  if ((int)blockIdx.x < t1b) {
    // ---- term1: min over pixels for each of this block's bins ----
    const int base = blockIdx.x * BPB;
    float bn[BPB], mn[BPB];
    #pragma unroll
    for (int k = 0; k < BPB; k++) {
      int bi = base + k;
      bn[k] = (bi < nb) ? bins[bi] * ib : 3e30f;
      mn[k] = 1e30f;
    }
    for (int i = threadIdx.x; i < n4; i += THREADS) {
      float4 a = t4[i];
      float tn[4] = {a.x * it, a.y * it, a.z * it, a.w * it};
      #pragma unroll
      for (int k = 0; k < BPB; k++) {
        #pragma unroll
        for (int c = 0; c < 4; c++) {
          float d = bn[k] - tn[c];
          mn[k] = fminf(mn[k], d * d);
        }
      }
    }
    for (int i = n4 * 4 + threadIdx.x; i < n; i += THREADS) {
      float tn = t[i] * it;
      #pragma unroll
      for (int k = 0; k < BPB; k++) {
        float d = bn[k] - tn;
        mn[k] = fminf(mn[k], d * d);
      }
    }
    __shared__ float sm[4 * BPB];
    #pragma unroll
    for (int k = 0; k < BPB; k++) {
      float m = wredMin(mn[k]);
      if (lane == 0) sm[wid * BPB + k] = m;
    }
    __syncthreads();
    if (threadIdx.x == 0) {
      float s = 0.0f;
      for (int k = 0; k < BPB; k++) {
        if (base + k < nb) {
          float m = fminf(fminf(sm[0 * BPB + k], sm[1 * BPB + k]),
                          fminf(sm[2 * BPB + k], sm[3 * BPB + k]));
          s += m;
        }
      }
      atomicAdd(wsum, (double)s);
    }
  } else {
    // ---- term2: per-pixel min over all bins ----
    __shared__ float bsh[1024];
    for (int i = threadIdx.x; i < nb && i < 1024; i += THREADS) bsh[i] = bins[i] * ib;
    __syncthreads();
    const int b2 = blockIdx.x - t1b;
    const int stride = (gridDim.x - t1b) * THREADS;
    float lsum = 0.0f;
    for (int i = b2 * THREADS + threadIdx.x; i < n4; i += stride) {
      float4 a = t4[i];
      float t0 = a.x * it, t1 = a.y * it, t2 = a.z * it, t3 = a.w * it;
      float m0 = 1e30f, m1 = 1e30f, m2 = 1e30f, m3 = 1e30f;
      #pragma unroll 4
      for (int j = 0; j < nb; j++) {
        float b = bsh[j];
        float d0 = t0 - b, d1 = t1 - b, d2 = t2 - b, d3 = t3 - b;
        m0 = fminf(m0, d0 * d0);
        m1 = fminf(m1, d1 * d1);
        m2 = fminf(m2, d2 * d2);
        m3 = fminf(m3, d3 * d3);
      }
      lsum += (m0 + m1) + (m2 + m3);
    }
    for (int i = n4 * 4 + b2 * THREADS + threadIdx.x; i < n; i += stride) {
      float tn = t[i] * it;
      float m = 1e30f;
      for (int j = 0; j < nb; j++) {
        float d = tn - bsh[j];
        m = fminf(m, d * d);
      }
      lsum += m;
    }
    __shared__ float ss[4];
    float s = wredSum(lsum);
    if (lane == 0) ss[wid] = s;
    __syncthreads();
    if (threadIdx.x == 0) atomicAdd(wsum, (double)((ss[0] + ss[1]) + (ss[2] + ss[3])));
  }
}

__global__ void k_fin(const double* __restrict__ wsum, float* __restrict__ out) {
  out[0] = (float)wsum[0];
}

extern "C" void kernel_launch(void* const* d_in, const int* in_sizes, int n_in,
                              void* d_out, int out_size, void* d_ws, size_t ws_size,
                              hipStream_t stream) {
  const float* target = (const float*)d_in[0];
  const float* bins = (const float*)d_in[1];
  const int n = in_sizes[0];   // 307200
  const int nb = in_sizes[1];  // 256
  float* out = (float*)d_out;

  unsigned int* wsu = (unsigned int*)d_ws;
  float* wsf = (float*)d_ws;
  double* wsum = (double*)((char*)d_ws + 8);

  const int n4 = n / 4;
  const float4* t4 = (const float4*)target;

  k_init<<<1, THREADS, 0, stream>>>(bins, nb, wsu, wsf, wsum);

  int gmax = (n4 + THREADS - 1) / THREADS;
  if (gmax > 512) gmax = 512;
  if (gmax < 1) gmax = 1;
  k_tmax<<<gmax, THREADS, 0, stream>>>(t4, n4, target, n, wsu);

  const int t1b = (nb + BPB - 1) / BPB;  // 32 blocks for term1
  const int n2b = 300;                   // term2 blocks: 300*256 threads = one float4 each
  k_main<<<t1b + n2b, THREADS, 0, stream>>>(t4, n4, target, n, bins, nb, wsu, wsf, wsum, t1b);

  k_fin<<<1, 1, 0, stream>>>(wsum, out);
}

// Round 2
// 78.322 us; speedup vs baseline: 2.3280x; 2.3280x over previous
//
#include <hip/hip_runtime.h>
#include <math.h>

#define THREADS 256
#define BPB 8    // bins per term1 block
#define PCH 16   // pixel chunks for term1 -> t1 blocks = (nb/BPB)*PCH

__device__ __forceinline__ float wredMax(float v) {
  #pragma unroll
  for (int o = 32; o > 0; o >>= 1) v = fmaxf(v, __shfl_down(v, o, 64));
  return v;
}
__device__ __forceinline__ float wredMin(float v) {
  #pragma unroll
  for (int o = 32; o > 0; o >>= 1) v = fminf(v, __shfl_down(v, o, 64));
  return v;
}
__device__ __forceinline__ float wredSum(float v) {
  #pragma unroll
  for (int o = 32; o > 0; o >>= 1) v += __shfl_down(v, o, 64);
  return v;
}

// ws layout:
//   [0..3]   uint  tmax bits      (memset 0; target>0 so uint order == float order)
//   [8..15]  double sum           (memset 0)
//   [16..16+4*nb) uint binmin[nb] (memset 0x7F -> 3.39e38 as float)

__global__ __launch_bounds__(THREADS) void k_tmax(const float4* __restrict__ t4, int n4,
                                                  const float* __restrict__ t, int n,
                                                  unsigned int* __restrict__ wsu) {
  __shared__ float sm[4];
  float v = 0.0f;
  int idx = blockIdx.x * THREADS + threadIdx.x;
  int stride = gridDim.x * THREADS;
  for (int i = idx; i < n4; i += stride) {
    float4 a = t4[i];
    v = fmaxf(v, fmaxf(fmaxf(a.x, a.y), fmaxf(a.z, a.w)));
  }
  for (int i = n4 * 4 + idx; i < n; i += stride) v = fmaxf(v, t[i]);
  v = wredMax(v);
  int lane = threadIdx.x & 63, wid = threadIdx.x >> 6;
  if (lane == 0) sm[wid] = v;
  __syncthreads();
  if (threadIdx.x == 0) {
    float m = fmaxf(fmaxf(sm[0], sm[1]), fmaxf(sm[2], sm[3]));
    atomicMax(wsu, __float_as_uint(m));
  }
}

// blocks [0, t1b):  term1 — block b owns bin-group b/PCH and pixel-chunk b%PCH;
//                   local min per bin, then atomicMin into binmin[].
// blocks [t1b, ..): term2 — per-pixel min over all bins (LDS), sum -> atomicAdd.
__global__ __launch_bounds__(THREADS) void k_main(const float4* __restrict__ t4, int n4,
                                                  const float* __restrict__ t, int n,
                                                  const float* __restrict__ bins, int nb,
                                                  const unsigned int* __restrict__ wsu,
                                                  double* __restrict__ wsum,
                                                  unsigned int* __restrict__ binmin,
                                                  int t1b) {
  __shared__ float sred[4];
  __shared__ float sm[4 * BPB];
  __shared__ float bsh[1024];

  const int lane = threadIdx.x & 63, wid = threadIdx.x >> 6;

  // every block computes the bins max locally (cheap: nb<=1024 loads + reduce)
  float bv = 0.0f;
  for (int i = threadIdx.x; i < nb; i += THREADS) bv = fmaxf(bv, bins[i]);
  bv = wredMax(bv);
  if (lane == 0) sred[wid] = bv;
  __syncthreads();
  const float ib = 1.0f / fmaxf(fmaxf(sred[0], sred[1]), fmaxf(sred[2], sred[3]));
  const float it = 1.0f / __uint_as_float(wsu[0]);
  __syncthreads();  // sred is dead; sm may alias timing-wise across waves

  if ((int)blockIdx.x < t1b) {
    // ---- term1 ----
    const int g = blockIdx.x / PCH;   // bin group
    const int c = blockIdx.x % PCH;   // pixel chunk
    const int base = g * BPB;
    float bn[BPB], mn[BPB];
    #pragma unroll
    for (int k = 0; k < BPB; k++) {
      int bi = base + k;
      bn[k] = (bi < nb) ? bins[bi] * ib : 3e30f;
      mn[k] = 1e30f;
    }
    const int chunk = (n4 + PCH - 1) / PCH;
    const int lo = c * chunk;
    const int hi = (lo + chunk < n4) ? lo + chunk : n4;
    for (int i = lo + threadIdx.x; i < hi; i += THREADS) {
      float4 a = t4[i];
      float tn[4] = {a.x * it, a.y * it, a.z * it, a.w * it};
      #pragma unroll
      for (int k = 0; k < BPB; k++) {
        #pragma unroll
        for (int cc = 0; cc < 4; cc++) {
          float d = bn[k] - tn[cc];
          mn[k] = fminf(mn[k], d * d);
        }
      }
    }
    if (c == 0) {
      for (int i = n4 * 4 + threadIdx.x; i < n; i += THREADS) {
        float tn = t[i] * it;
        #pragma unroll
        for (int k = 0; k < BPB; k++) {
          float d = bn[k] - tn;
          mn[k] = fminf(mn[k], d * d);
        }
      }
    }
    #pragma unroll
    for (int k = 0; k < BPB; k++) {
      float m = wredMin(mn[k]);
      if (lane == 0) sm[wid * BPB + k] = m;
    }
    __syncthreads();
    if (threadIdx.x < BPB) {
      int k = threadIdx.x;
      if (base + k < nb) {
        float m = fminf(fminf(sm[k], sm[BPB + k]), fminf(sm[2 * BPB + k], sm[3 * BPB + k]));
        atomicMin(&binmin[base + k], __float_as_uint(m));
      }
    }
  } else {
    // ---- term2 ----
    for (int i = threadIdx.x; i < nb && i < 1024; i += THREADS) bsh[i] = bins[i] * ib;
    __syncthreads();
    const int b2 = blockIdx.x - t1b;
    const int stride = (gridDim.x - t1b) * THREADS;
    float lsum = 0.0f;
    for (int i = b2 * THREADS + threadIdx.x; i < n4; i += stride) {
      float4 a = t4[i];
      float t0 = a.x * it, t1 = a.y * it, t2 = a.z * it, t3 = a.w * it;
      float m0 = 1e30f, m1 = 1e30f, m2 = 1e30f, m3 = 1e30f;
      #pragma unroll 4
      for (int j = 0; j < nb; j++) {
        float b = bsh[j];
        float d0 = t0 - b, d1 = t1 - b, d2 = t2 - b, d3 = t3 - b;
        m0 = fminf(m0, d0 * d0);
        m1 = fminf(m1, d1 * d1);
        m2 = fminf(m2, d2 * d2);
        m3 = fminf(m3, d3 * d3);
      }
      lsum += (m0 + m1) + (m2 + m3);
    }
    for (int i = n4 * 4 + b2 * THREADS + threadIdx.x; i < n; i += stride) {
      float tn = t[i] * it;
      float m = 1e30f;
      for (int j = 0; j < nb; j++) {
        float d = tn - bsh[j];
        m = fminf(m, d * d);
      }
      lsum += m;
    }
    float s = wredSum(lsum);
    if (lane == 0) sred[wid] = s;
    __syncthreads();
    if (threadIdx.x == 0)
      atomicAdd(wsum, (double)((sred[0] + sred[1]) + (sred[2] + sred[3])));
  }
}

__global__ __launch_bounds__(THREADS) void k_fin(const unsigned int* __restrict__ binmin, int nb,
                                                 const double* __restrict__ wsum,
                                                 float* __restrict__ out) {
  __shared__ float sm[4];
  float s = 0.0f;
  for (int i = threadIdx.x; i < nb; i += THREADS) {
    float m = __uint_as_float(binmin[i]);
    s += (m < 1e30f) ? m : 0.0f;
  }
  s = wredSum(s);
  int lane = threadIdx.x & 63, wid = threadIdx.x >> 6;
  if (lane == 0) sm[wid] = s;
  __syncthreads();
  if (threadIdx.x == 0)
    out[0] = (float)(wsum[0] + (double)((sm[0] + sm[1]) + (sm[2] + sm[3])));
}

extern "C" void kernel_launch(void* const* d_in, const int* in_sizes, int n_in,
                              void* d_out, int out_size, void* d_ws, size_t ws_size,
                              hipStream_t stream) {
  const float* target = (const float*)d_in[0];
  const float* bins = (const float*)d_in[1];
  const int n = in_sizes[0];   // 307200
  const int nb = in_sizes[1];  // 256
  float* out = (float*)d_out;

  unsigned int* wsu = (unsigned int*)d_ws;
  double* wsum = (double*)((char*)d_ws + 8);
  unsigned int* binmin = (unsigned int*)((char*)d_ws + 16);

  const int n4 = n / 4;
  const float4* t4 = (const float4*)target;

  // init: tmax=0, sum=0.0, binmin[i]=0x7F7F7F7F (~3.39e38)
  hipMemsetAsync(d_ws, 0, 16, stream);
  hipMemsetAsync((char*)d_ws + 16, 0x7F, (size_t)4 * nb, stream);

  int gmax = (n4 + THREADS - 1) / THREADS;
  if (gmax > 512) gmax = 512;
  if (gmax < 1) gmax = 1;
  k_tmax<<<gmax, THREADS, 0, stream>>>(t4, n4, target, n, wsu);

  const int t1b = ((nb + BPB - 1) / BPB) * PCH;  // 32*16 = 512 blocks for term1
  const int n2b = 300;                            // term2: one float4 per thread
  k_main<<<t1b + n2b, THREADS, 0, stream>>>(t4, n4, target, n, bins, nb, wsu, wsum, binmin, t1b);

  k_fin<<<1, THREADS, 0, stream>>>(binmin, nb, wsum, out);
}